// Round 4
// baseline (1265.104 us; speedup 1.0000x reference)
//
#include <hip/hip_runtime.h>
#include <stdint.h>

#define DIM 512
#define BM 128    // rows per workgroup (fp32 fallback)
#define BK 128    // codebook entries per k-tile (fp32 fallback)
#define BD 32     // D-chunk staged in LDS (fp32 fallback)
#define LDP 132   // padded LDS leading dim (floats, fp32 fallback)
// Flag thresholds: reference distances are quantized at ulp(512) = 6.1e-5 by
// the +||z||^2 addition -> any code within 2*ulp of the partial min can win.
// fp32 screen error ~1e-7:            TAU  = 2*6.104e-5 + slack
// bf16x3 MFMA screen error ~2.4e-5:   TAU2 = 2*6.104e-5 + 2*2.4e-5 + slack
#define TAU  1.5e-4f
#define TAU2 2.0e-4f
// fixup shortlist window: must cover 1.5*ulp(512) + 2*fp32-prescreen-error
// (~9.8e-5); 2.05e-4 gives 2x margin.
#define FWIN 2.05e-4f
#define FR 16     // fixup rows batched per codebook pass

typedef __attribute__((ext_vector_type(8))) __bf16 bf16x8;
typedef __attribute__((ext_vector_type(4))) float  f32x4;

// ---------------------------------------------------------------------------
// ||e_k||^2: fp64 accumulation of fp32 (e*e) terms, rounded once to fp32.
// Also zeroes the flag counter.
__global__ __launch_bounds__(256) void enorm_kernel(const float* __restrict__ e,
                                                    float* __restrict__ enorm,
                                                    int* __restrict__ count, int K) {
    if (blockIdx.x == 0 && threadIdx.x == 0 && count) *count = 0;
    int w = (blockIdx.x * 256 + threadIdx.x) >> 6;
    int lane = threadIdx.x & 63;
    if (w >= K) return;
    const float4* e4 = (const float4*)(e + (size_t)w * DIM);
    float4 a = e4[lane];
    float4 b = e4[lane + 64];
    float t0 = a.x*a.x, t1 = a.y*a.y, t2 = a.z*a.z, t3 = a.w*a.w;
    float t4 = b.x*b.x, t5 = b.y*b.y, t6 = b.z*b.z, t7 = b.w*b.w;
    double s = ((double)t0 + (double)t1) + ((double)t2 + (double)t3)
             + ((double)t4 + (double)t5) + ((double)t6 + (double)t7);
    #pragma unroll
    for (int off = 32; off > 0; off >>= 1) s += __shfl_down(s, off, 64);
    if (lane == 0) enorm[w] = (float)s;
}

// ---------------------------------------------------------------------------
// bf16 split helpers (RNE; data is finite, no NaN/Inf handling needed)
__device__ __forceinline__ ushort bf16_rne(float x) {
    uint32_t u = __float_as_uint(x);
    uint32_t r = (u + 0x7fffu + ((u >> 16) & 1u)) >> 16;
    return (ushort)r;
}
__device__ __forceinline__ float bf16_f(ushort h) {
    return __uint_as_float(((uint32_t)h) << 16);
}

// Pre-convert z and e to bf16 hi/lo pairs (memory-bound).
__global__ __launch_bounds__(256) void cvt_kernel(const float* __restrict__ z,
                                                  const float* __restrict__ e,
                                                  ushort* __restrict__ zh, ushort* __restrict__ zl,
                                                  ushort* __restrict__ eh, ushort* __restrict__ el,
                                                  long nz4, long ne4) {
    long total = nz4 + ne4;
    for (long i = (long)blockIdx.x * 256 + threadIdx.x; i < total;
         i += (long)gridDim.x * 256) {
        const float4* s; ushort* dh; ushort* dl; long j;
        if (i < nz4) { s = (const float4*)z; dh = zh; dl = zl; j = i; }
        else         { s = (const float4*)e; dh = eh; dl = el; j = i - nz4; }
        float4 v = s[j];
        ushort h0 = bf16_rne(v.x), h1 = bf16_rne(v.y);
        ushort h2 = bf16_rne(v.z), h3 = bf16_rne(v.w);
        ushort l0 = bf16_rne(v.x - bf16_f(h0));
        ushort l1 = bf16_rne(v.y - bf16_f(h1));
        ushort l2 = bf16_rne(v.z - bf16_f(h2));
        ushort l3 = bf16_rne(v.w - bf16_f(h3));
        *(ushort4*)(dh + j * 4) = make_ushort4(h0, h1, h2, h3);
        *(ushort4*)(dl + j * 4) = make_ushort4(l0, l1, l2, l3);
    }
}

// ---------------------------------------------------------------------------
// MFMA screen: D[code][zrow] = e.z via 3-product bf16 split.
// (verified working r3: flag rate ~8-12%, fixup-repaired rows pass exactly)
__global__ __launch_bounds__(256, 2) void vq_mfma_kernel(
        const ushort* __restrict__ zh, const ushort* __restrict__ zl,
        const ushort* __restrict__ eh, const ushort* __restrict__ el,
        const float* __restrict__ enorm, const float* __restrict__ e,
        float* __restrict__ out, int* __restrict__ count, int* __restrict__ list,
        int cap, int N, int K) {
    __shared__ __align__(16) ushort tiles[4][8192];   // 64 KB total

    const int tid = threadIdx.x;
    const int w = tid >> 6, lane = tid & 63;
    const int wm = w >> 1, wn = w & 1;
    const int n0 = blockIdx.x * 128;

    const ushort* tsrc = (w == 0) ? eh : (w == 1) ? el : (w == 2) ? zh : zl;
    const bool is_e = (w < 2);

    const int srow = lane >> 3;            // staging: row within 8-row group
    const int skg  = lane & 7;             // staging: k-group (8 ushorts)
    const int swz  = (skg ^ srow) * 8;     // swizzled k-offset (row&7 == srow)

    const ushort* EH = tiles[0];
    const ushort* EL = tiles[1];
    const ushort* ZH = tiles[2];
    const ushort* ZL = tiles[3];

    float bv[4], sv[4]; int bi[4];
    #pragma unroll
    for (int b = 0; b < 4; b++) { bv[b] = 3.4e38f; sv[b] = 3.4e38f; bi[b] = 0; }

    const int rsel = lane & 15;

    for (int kt = 0; kt < K; kt += 128) {
        f32x4 acc[4][4];
        const f32x4 zero4 = {0.f, 0.f, 0.f, 0.f};
        #pragma unroll
        for (int a = 0; a < 4; a++)
            #pragma unroll
            for (int b = 0; b < 4; b++) acc[a][b] = zero4;

        const int rb = is_e ? kt : n0;
        const ushort* gsrc = tsrc + (size_t)(rb + srow) * DIM;

        for (int d0 = 0; d0 < DIM; d0 += 64) {
            // ---- stage this wave's tile: 128 rows x 64 k (16 KB) ----
            const ushort* gp = gsrc + d0 + skg * 8;
            {
                float4 stg[8];
                #pragma unroll
                for (int i = 0; i < 8; i++)
                    stg[i] = *(const float4*)(gp + (size_t)(8 * i) * DIM);
                #pragma unroll
                for (int i = 0; i < 8; i++)
                    *(float4*)&tiles[w][(8 * i + srow) * 64 + swz] = stg[i];
                #pragma unroll
                for (int i = 0; i < 8; i++)
                    stg[i] = *(const float4*)(gp + (size_t)(64 + 8 * i) * DIM);
                #pragma unroll
                for (int i = 0; i < 8; i++)
                    *(float4*)&tiles[w][(64 + 8 * i + srow) * 64 + swz] = stg[i];
            }
            __syncthreads();

            // ---- MFMA: 2 k-steps of 32, 3 products each ----
            #pragma unroll
            for (int c = 0; c < 2; c++) {
                const int rkg = ((c * 4 + (lane >> 4)) ^ (lane & 7)) * 8;
                bf16x8 Ah[4], Al[4];
                #pragma unroll
                for (int a = 0; a < 4; a++) {
                    int off = (wm * 64 + a * 16 + rsel) * 64 + rkg;
                    Ah[a] = *(const bf16x8*)&EH[off];
                    Al[a] = *(const bf16x8*)&EL[off];
                }
                #pragma unroll
                for (int b = 0; b < 4; b++) {
                    int off = (wn * 64 + b * 16 + rsel) * 64 + rkg;
                    bf16x8 Bh = *(const bf16x8*)&ZH[off];
                    bf16x8 Bl = *(const bf16x8*)&ZL[off];
                    #pragma unroll
                    for (int a = 0; a < 4; a++) {
                        acc[a][b] = __builtin_amdgcn_mfma_f32_16x16x32_bf16(Ah[a], Bh, acc[a][b], 0, 0, 0);
                        acc[a][b] = __builtin_amdgcn_mfma_f32_16x16x32_bf16(Al[a], Bh, acc[a][b], 0, 0, 0);
                        acc[a][b] = __builtin_amdgcn_mfma_f32_16x16x32_bf16(Ah[a], Bl, acc[a][b], 0, 0, 0);
                    }
                }
            }
            __syncthreads();
        }
        // epilogue: s = ||e||^2 - 2*dot; per-lane codes scan ascending (a outer,
        // r inner) so plain (s < bv) keeps first-min within this lane.
        const int hi4 = (lane >> 4) * 4;
        #pragma unroll
        for (int a = 0; a < 4; a++) {
            #pragma unroll
            for (int r = 0; r < 4; r++) {
                const int code = kt + wm * 64 + a * 16 + hi4 + r;
                const float en = enorm[code];   // 4KB, L1-resident
                #pragma unroll
                for (int b = 0; b < 4; b++) {
                    float s = fmaf(-2.f, acc[a][b][r], en);
                    if (s < bv[b]) { sv[b] = bv[b]; bv[b] = s; bi[b] = code; }
                    else if (s < sv[b]) sv[b] = s;
                }
            }
        }
    }

    // merge across the 4 hi-groups (lanes l, l^16, l^32, l^48 share zrows);
    // lexicographic (val, idx) preserves first-min across interleaved codes.
    #pragma unroll
    for (int off = 16; off <= 32; off <<= 1) {
        #pragma unroll
        for (int b = 0; b < 4; b++) {
            float obv = __shfl_xor(bv[b], off, 64);
            float osv = __shfl_xor(sv[b], off, 64);
            int   obi = __shfl_xor(bi[b], off, 64);
            if (obv < bv[b] || (obv == bv[b] && obi < bi[b])) {
                sv[b] = fminf(osv, fminf(sv[b], bv[b]));
                bv[b] = obv; bi[b] = obi;
            } else {
                sv[b] = fminf(sv[b], fminf(osv, obv));
            }
        }
    }

    // union: red arrays alias tile memory (tiles dead after last d0 barrier)
    char* ub = (char*)tiles;
    float* redv = (float*)ub;            // [128][2]
    float* reds = (float*)(ub + 1024);   // [128][2]
    int*   redi = (int*)  (ub + 2048);   // [128][2]
    int*   bestk = (int*) (ub + 3072);   // [128]

    if (lane < 16) {
        #pragma unroll
        for (int b = 0; b < 4; b++) {
            int rl = wn * 64 + b * 16 + lane;
            redv[rl * 2 + wm] = bv[b];
            reds[rl * 2 + wm] = sv[b];
            redi[rl * 2 + wm] = bi[b];
        }
    }
    __syncthreads();
    if (tid < 128) {
        float v  = redv[tid * 2 + 0], s2  = reds[tid * 2 + 0];
        int   ix = redi[tid * 2 + 0];
        float v2 = redv[tid * 2 + 1], s22 = reds[tid * 2 + 1];
        int   i2 = redi[tid * 2 + 1];
        if (v2 < v || (v2 == v && i2 < ix)) {
            s2 = fminf(s22, fminf(s2, v)); v = v2; ix = i2;
        } else {
            s2 = fminf(s2, fminf(s22, v2));
        }
        bestk[tid] = ix;
        if (count && (s2 - v < TAU2)) {   // quantized argmin may differ -> flag
            int slot = atomicAdd(count, 1);
            if (slot < cap) list[slot] = n0 + tid;
        }
    }
    __syncthreads();

    // Gather: out[row] = e[bestk[row]]
    const float4* e4 = (const float4*)e;
    float4* o4 = (float4*)out;
    for (int j = tid; j < 128 * (DIM / 4); j += 256) {
        int row = j >> 7;
        int col = j & 127;
        o4[(size_t)(n0 + row) * (DIM / 4) + col] = e4[(size_t)bestk[row] * (DIM / 4) + col];
    }
}

// ---------------------------------------------------------------------------
// fp32 fallback screen — used only when ws is too small for bf16 workspace.
__global__ __launch_bounds__(256, 2) void vq_kernel(const float* __restrict__ z,
                                                    const float* __restrict__ e,
                                                    const float* __restrict__ enorm,
                                                    float* __restrict__ out,
                                                    int* __restrict__ count,
                                                    int* __restrict__ list,
                                                    int cap, int N, int K) {
    __shared__ __align__(16) float zs[BD * LDP];
    __shared__ __align__(16) float es[BD * LDP];
    __shared__ float redv[BM * 16];
    __shared__ int   redi[BM * 16];
    __shared__ float reds[BM * 16];
    __shared__ int   bestk[BM];

    const int tid = threadIdx.x;
    const int tx = tid & 15;
    const int ty = tid >> 4;
    const int n0 = blockIdx.x * BM;

    float bv[8], sv[8];
    int   bi[8];
    #pragma unroll
    for (int i = 0; i < 8; i++) { bv[i] = 3.4e38f; sv[i] = 3.4e38f; bi[i] = 0; }

    for (int kt = 0; kt < K; kt += BK) {
        float acc[8][8];
        #pragma unroll
        for (int i = 0; i < 8; i++)
            #pragma unroll
            for (int j = 0; j < 8; j++) acc[i][j] = 0.f;

        for (int d0 = 0; d0 < DIM; d0 += BD) {
            #pragma unroll
            for (int l = 0; l < 4; l++) {
                int j = tid + l * 256;
                int row = j >> 3;
                int c = j & 7;
                float4 v = *(const float4*)(z + (size_t)(n0 + row) * DIM + d0 + c * 4);
                zs[(c*4+0)*LDP + row] = v.x;
                zs[(c*4+1)*LDP + row] = v.y;
                zs[(c*4+2)*LDP + row] = v.z;
                zs[(c*4+3)*LDP + row] = v.w;
                float4 w = *(const float4*)(e + (size_t)(kt + row) * DIM + d0 + c * 4);
                es[(c*4+0)*LDP + row] = w.x;
                es[(c*4+1)*LDP + row] = w.y;
                es[(c*4+2)*LDP + row] = w.z;
                es[(c*4+3)*LDP + row] = w.w;
            }
            __syncthreads();
            #pragma unroll 8
            for (int dd = 0; dd < BD; dd++) {
                float4 z0 = *(const float4*)&zs[dd*LDP + ty*8];
                float4 z1 = *(const float4*)&zs[dd*LDP + ty*8+4];
                float4 e0 = *(const float4*)&es[dd*LDP + tx*4];
                float4 e1 = *(const float4*)&es[dd*LDP + tx*4+64];
                float zr[8] = {z0.x, z0.y, z0.z, z0.w, z1.x, z1.y, z1.z, z1.w};
                float ek[8] = {e0.x, e0.y, e0.z, e0.w, e1.x, e1.y, e1.z, e1.w};
                #pragma unroll
                for (int i = 0; i < 8; i++)
                    #pragma unroll
                    for (int jj = 0; jj < 8; jj++)
                        acc[i][jj] = fmaf(zr[i], ek[jj], acc[i][jj]);
            }
            __syncthreads();
        }
        #pragma unroll
        for (int jj = 0; jj < 8; jj++) {
            int kk = kt + ((jj < 4) ? (tx*4 + jj) : (64 + tx*4 + (jj - 4)));
            float en = enorm[kk];
            #pragma unroll
            for (int i = 0; i < 8; i++) {
                float s = fmaf(-2.f, acc[i][jj], en);
                if (s < bv[i]) { sv[i] = bv[i]; bv[i] = s; bi[i] = kk; }
                else if (s < sv[i]) sv[i] = s;
            }
        }
    }

    #pragma unroll
    for (int i = 0; i < 8; i++) {
        int row = ty*8 + i;
        redv[row*16 + tx] = bv[i];
        redi[row*16 + tx] = bi[i];
        reds[row*16 + tx] = sv[i];
    }
    __syncthreads();
    if (tid < BM) {
        float v = redv[tid*16];
        int ix = redi[tid*16];
        float s2 = reds[tid*16];
        #pragma unroll
        for (int t = 1; t < 16; t++) {
            float v2 = redv[tid*16 + t];
            int i2 = redi[tid*16 + t];
            float s22 = reds[tid*16 + t];
            if (v2 < v || (v2 == v && i2 < ix)) { s2 = fminf(s22, v); v = v2; ix = i2; }
            else { s2 = fminf(s2, v2); }
        }
        bestk[tid] = ix;
        if (count && (s2 - v < TAU)) {
            int slot = atomicAdd(count, 1);
            if (slot < cap) list[slot] = n0 + tid;
        }
    }
    __syncthreads();

    const float4* e4 = (const float4*)e;
    float4* o4 = (float4*)out;
    for (int j = tid; j < BM * (DIM / 4); j += 256) {
        int row = j >> 7;
        int col = j & 127;
        o4[(size_t)(n0 + row) * (DIM / 4) + col] = e4[(size_t)bestk[row] * (DIM / 4) + col];
    }
}

// ---------------------------------------------------------------------------
// Batched fixup: 16 flagged rows share one codebook pass.
// Pass A: fp32 partial scores p = ||e||^2 - 2 z.e for 4 codes/thread x 16 rows
//         (error <~3e-6), per-row fp32 min via wave+LDS reduce.
// Pass B: exact replica D = fl32( fl32(Z+E_k) - 2*fl32(dot64) ) ONLY for codes
//         with p <= rmin + FWIN (superset of all quantized-argmin candidates,
//         since any candidate's partial is within 1.5*ulp(512)+2*err of min).
//         Codes ascend per thread; lexicographic (D, idx) reduce -> first-min.
__global__ __launch_bounds__(256) void fixup2_kernel(const float* __restrict__ z,
                                                     const float* __restrict__ e,
                                                     const float* __restrict__ enorm,
                                                     float* __restrict__ out,
                                                     const int* __restrict__ count,
                                                     const int* __restrict__ list,
                                                     int cap, int K) {
    __shared__ __align__(16) float zs[FR][DIM];   // 32 KB
    __shared__ double zred[FR][16];
    __shared__ float  Zs[FR];
    __shared__ float  rminw[FR][4];
    __shared__ float  rvD[FR][4];
    __shared__ int    rvI[FR][4];
    __shared__ int    bk[FR];

    if (!count) return;
    int cnt = *count;
    if (cnt > cap) cnt = cap;
    const int tid = threadIdx.x, lane = tid & 63, wv = tid >> 6;

    for (int base = blockIdx.x * FR; base < cnt; base += gridDim.x * FR) {
        const int rows = (cnt - base < FR) ? (cnt - base) : FR;
        __syncthreads();   // protect zs/bk reuse across outer iterations
        // ---- stage z rows (fp32) ----
        for (int q = tid; q < FR * (DIM / 4); q += 256) {
            int rr = q >> 7, c = q & 127;
            float4 v = make_float4(0.f, 0.f, 0.f, 0.f);
            if (rr < rows) v = ((const float4*)(z + (size_t)list[base + rr] * DIM))[c];
            ((float4*)zs[rr])[c] = v;
        }
        __syncthreads();
        // ---- Z per row: fp64 sum of fl32(z*z) terms ----
        {
            int rr = tid >> 4, part = tid & 15;
            double s = 0.0;
            #pragma unroll 8
            for (int j = part * 32; j < part * 32 + 32; j++) {
                float f = zs[rr][j]; float t = f * f; s += (double)t;
            }
            zred[rr][part] = s;
        }
        __syncthreads();
        if (tid < FR) {
            double s = 0.0;
            #pragma unroll
            for (int p = 0; p < 16; p++) s += zred[tid][p];
            Zs[tid] = (float)s;
        }
        __syncthreads();

        // ---- pass A: fp32 partial scores, 4 codes x 16 rows ----
        const float4* ep[4];
        #pragma unroll
        for (int q = 0; q < 4; q++)
            ep[q] = (const float4*)(e + (size_t)(tid + 256 * q) * DIM);

        float pD[4][FR];
        #pragma unroll
        for (int q = 0; q < 4; q++)
            #pragma unroll
            for (int rr = 0; rr < FR; rr++) pD[q][rr] = 0.f;

        for (int d4 = 0; d4 < DIM / 4; d4++) {
            float4 ev[4];
            #pragma unroll
            for (int q = 0; q < 4; q++) ev[q] = ep[q][d4];
            #pragma unroll
            for (int g = 0; g < 4; g++) {
                float4 zv[4];
                #pragma unroll
                for (int j = 0; j < 4; j++) zv[j] = ((const float4*)zs[g * 4 + j])[d4];
                #pragma unroll
                for (int q = 0; q < 4; q++)
                    #pragma unroll
                    for (int j = 0; j < 4; j++) {
                        float a = pD[q][g * 4 + j];
                        a = fmaf(ev[q].x, zv[j].x, a);
                        a = fmaf(ev[q].y, zv[j].y, a);
                        a = fmaf(ev[q].z, zv[j].z, a);
                        a = fmaf(ev[q].w, zv[j].w, a);
                        pD[q][g * 4 + j] = a;
                    }
            }
        }
        #pragma unroll
        for (int q = 0; q < 4; q++) {
            float en = enorm[tid + 256 * q];
            #pragma unroll
            for (int rr = 0; rr < FR; rr++)
                pD[q][rr] = fmaf(-2.f, pD[q][rr], en);
        }
        // per-row fp32 min: thread -> wave -> block
        #pragma unroll
        for (int rr = 0; rr < FR; rr++) {
            float m = fminf(fminf(pD[0][rr], pD[1][rr]), fminf(pD[2][rr], pD[3][rr]));
            #pragma unroll
            for (int off = 32; off > 0; off >>= 1) m = fminf(m, __shfl_xor(m, off, 64));
            if (lane == 0) rminw[rr][wv] = m;
        }
        __syncthreads();
        float rmin[FR];
        #pragma unroll
        for (int rr = 0; rr < FR; rr++)
            rmin[rr] = fminf(fminf(rminw[rr][0], rminw[rr][1]),
                             fminf(rminw[rr][2], rminw[rr][3]));

        // ---- pass B: exact fp64 replica on shortlist ----
        float bD[FR]; int bI[FR];
        #pragma unroll
        for (int rr = 0; rr < FR; rr++) { bD[rr] = 3.4e38f; bI[rr] = 0x7fffffff; }
        #pragma unroll
        for (int q = 0; q < 4; q++) {
            const int c = tid + 256 * q;
            #pragma unroll
            for (int rr = 0; rr < FR; rr++) {
                if (pD[q][rr] <= rmin[rr] + FWIN) {
                    double s = 0.0;
                    #pragma unroll 4
                    for (int d4 = 0; d4 < DIM / 4; d4++) {
                        float4 evv = ep[q][d4];
                        const float* zr = &zs[rr][d4 * 4];
                        s = fma((double)zr[0], (double)evv.x, s);
                        s = fma((double)zr[1], (double)evv.y, s);
                        s = fma((double)zr[2], (double)evv.z, s);
                        s = fma((double)zr[3], (double)evv.w, s);
                    }
                    float m = (float)s;              // fl32(dot64)
                    float T = Zs[rr] + enorm[c];     // fl32(Z + E_k)
                    float D = T - 2.0f * m;          // fl32(T - 2m)
                    if (D < bD[rr]) { bD[rr] = D; bI[rr] = c; }
                }
            }
        }
        // lexicographic (D, idx) reduce: wave -> block
        #pragma unroll
        for (int rr = 0; rr < FR; rr++) {
            float D = bD[rr]; int I = bI[rr];
            #pragma unroll
            for (int off = 32; off > 0; off >>= 1) {
                float oD = __shfl_xor(D, off, 64);
                int   oI = __shfl_xor(I, off, 64);
                if (oD < D || (oD == D && oI < I)) { D = oD; I = oI; }
            }
            if (lane == 0) { rvD[rr][wv] = D; rvI[rr][wv] = I; }
        }
        __syncthreads();
        if (tid < FR) {
            float D = rvD[tid][0]; int I = rvI[tid][0];
            #pragma unroll
            for (int w2 = 1; w2 < 4; w2++) {
                float oD = rvD[tid][w2]; int oI = rvI[tid][w2];
                if (oD < D || (oD == D && oI < I)) { D = oD; I = oI; }
            }
            bk[tid] = I;
        }
        __syncthreads();
        // ---- write out[row] = e[bk[rr]] ----
        for (int q = tid; q < rows * (DIM / 4); q += 256) {
            int rr = q >> 7, c = q & 127;
            ((float4*)(out + (size_t)list[base + rr] * DIM))[c] =
                ((const float4*)(e + (size_t)bk[rr] * DIM))[c];
        }
    }
}

// ---------------------------------------------------------------------------
extern "C" void kernel_launch(void* const* d_in, const int* in_sizes, int n_in,
                              void* d_out, int out_size, void* d_ws, size_t ws_size,
                              hipStream_t stream) {
    const float* z = (const float*)d_in[0];
    const float* e = (const float*)d_in[1];
    float* out = (float*)d_out;
    const int N = in_sizes[0] / DIM;   // 65536
    const int K = in_sizes[1] / DIM;   // 1024

    // ws layout: [0,K) enorm | [K] count | [K+1,K+1+N) list | 4KB-aligned:
    //            zh[N*D] zl[N*D] eh[K*D] el[K*D]  (bf16 as ushort)
    float* enorm = (float*)d_ws;
    long ws_elems = (long)(ws_size / 4);
    bool have_list = ws_elems >= K + 2;
    int* count = have_list ? ((int*)d_ws + K) : nullptr;
    int* list  = have_list ? ((int*)d_ws + K + 1) : nullptr;

    size_t base_b  = (size_t)(K + 1 + N) * 4;
    size_t cvt_off = (base_b + 4095) & ~(size_t)4095;
    size_t zpart   = (size_t)N * DIM * 2;
    size_t epart   = (size_t)K * DIM * 2;
    size_t need    = cvt_off + 2 * zpart + 2 * epart;
    bool mfma_ok = have_list && ws_size >= need && K == 1024 && (N % 128) == 0;

    if (mfma_ok) {
        int cap = N;   // list region sized N ints, disjoint from bf16 region
        ushort* zh = (ushort*)((char*)d_ws + cvt_off);
        ushort* zl = zh + (size_t)N * DIM;
        ushort* eh = zl + (size_t)N * DIM;
        ushort* el = eh + (size_t)K * DIM;
        long nz4 = (long)N * (DIM / 4), ne4 = (long)K * (DIM / 4);
        cvt_kernel<<<dim3(2048), dim3(256), 0, stream>>>(z, e, zh, zl, eh, el, nz4, ne4);
        enorm_kernel<<<dim3((K + 3) / 4), dim3(256), 0, stream>>>(e, enorm, count, K);
        vq_mfma_kernel<<<dim3(N / 128), dim3(256), 0, stream>>>(zh, zl, eh, el, enorm, e,
                                                                out, count, list, cap, N, K);
        fixup2_kernel<<<dim3(2048), dim3(256), 0, stream>>>(z, e, enorm, out, count, list, cap, K);
    } else {
        long cap_l = have_list ? (ws_elems - K - 1) : 0;
        int cap = cap_l > N ? N : (int)cap_l;
        enorm_kernel<<<dim3((K + 3) / 4), dim3(256), 0, stream>>>(e, enorm, count, K);
        vq_kernel<<<dim3(N / BM), dim3(256), 0, stream>>>(z, e, enorm, out, count, list, cap, N, K);
        fixup2_kernel<<<dim3(2048), dim3(256), 0, stream>>>(z, e, enorm, out, count, list, cap, K);
    }
}

// Round 5
// 556.082 us; speedup vs baseline: 2.2750x; 2.2750x over previous
//
#include <hip/hip_runtime.h>
#include <stdint.h>

#define DIM 512
#define BM 128    // rows per workgroup (fp32 fallback)
#define BK 128    // codebook entries per k-tile (fp32 fallback)
#define BD 32     // D-chunk staged in LDS (fp32 fallback)
#define LDP 132   // padded LDS leading dim (floats, fp32 fallback)
// Flag threshold: reference distances are quantized at ulp(512) = 6.1e-5 by
// the +||z||^2 addition -> any code within 2*ulp (+ screen error) of the best
// can win at the quantized level. 2*6.1e-5 + screen-err margin:
#define TAU2 2.0e-4f
#define TAU  1.5e-4f   // fp32 fallback screen

typedef __attribute__((ext_vector_type(8))) __bf16 bf16x8;
typedef __attribute__((ext_vector_type(4))) float  f32x4;

// ---------------------------------------------------------------------------
// ||e_k||^2: fp64 accumulation of fp32 (e*e) terms, rounded once to fp32.
// Also zeroes both flag counters ([0]=full, [1]=lite).
__global__ __launch_bounds__(256) void enorm_kernel(const float* __restrict__ e,
                                                    float* __restrict__ enorm,
                                                    int* __restrict__ count, int K) {
    if (blockIdx.x == 0 && threadIdx.x == 0 && count) { count[0] = 0; count[1] = 0; }
    int w = (blockIdx.x * 256 + threadIdx.x) >> 6;
    int lane = threadIdx.x & 63;
    if (w >= K) return;
    const float4* e4 = (const float4*)(e + (size_t)w * DIM);
    float4 a = e4[lane];
    float4 b = e4[lane + 64];
    float t0 = a.x*a.x, t1 = a.y*a.y, t2 = a.z*a.z, t3 = a.w*a.w;
    float t4 = b.x*b.x, t5 = b.y*b.y, t6 = b.z*b.z, t7 = b.w*b.w;
    double s = ((double)t0 + (double)t1) + ((double)t2 + (double)t3)
             + ((double)t4 + (double)t5) + ((double)t6 + (double)t7);
    #pragma unroll
    for (int off = 32; off > 0; off >>= 1) s += __shfl_down(s, off, 64);
    if (lane == 0) enorm[w] = (float)s;
}

// ---------------------------------------------------------------------------
// bf16 split helpers (RNE; data is finite)
__device__ __forceinline__ ushort bf16_rne(float x) {
    uint32_t u = __float_as_uint(x);
    uint32_t r = (u + 0x7fffu + ((u >> 16) & 1u)) >> 16;
    return (ushort)r;
}
__device__ __forceinline__ float bf16_f(ushort h) {
    return __uint_as_float(((uint32_t)h) << 16);
}

// Pre-convert z and e to bf16 hi/lo pairs (memory-bound).
__global__ __launch_bounds__(256) void cvt_kernel(const float* __restrict__ z,
                                                  const float* __restrict__ e,
                                                  ushort* __restrict__ zh, ushort* __restrict__ zl,
                                                  ushort* __restrict__ eh, ushort* __restrict__ el,
                                                  long nz4, long ne4) {
    long total = nz4 + ne4;
    for (long i = (long)blockIdx.x * 256 + threadIdx.x; i < total;
         i += (long)gridDim.x * 256) {
        const float4* s; ushort* dh; ushort* dl; long j;
        if (i < nz4) { s = (const float4*)z; dh = zh; dl = zl; j = i; }
        else         { s = (const float4*)e; dh = eh; dl = el; j = i - nz4; }
        float4 v = s[j];
        ushort h0 = bf16_rne(v.x), h1 = bf16_rne(v.y);
        ushort h2 = bf16_rne(v.z), h3 = bf16_rne(v.w);
        ushort l0 = bf16_rne(v.x - bf16_f(h0));
        ushort l1 = bf16_rne(v.y - bf16_f(h1));
        ushort l2 = bf16_rne(v.z - bf16_f(h2));
        ushort l3 = bf16_rne(v.w - bf16_f(h3));
        *(ushort4*)(dh + j * 4) = make_ushort4(h0, h1, h2, h3);
        *(ushort4*)(dl + j * 4) = make_ushort4(l0, l1, l2, l3);
    }
}

// ---------------------------------------------------------------------------
// lexicographic (val, idx) helpers for top-4 lists
__device__ __forceinline__ void minL(float av, int ai, float bv, int bi,
                                     float& ov, int& oi) {
    bool t = (bv < av) || (bv == av && bi < ai);
    ov = t ? bv : av; oi = t ? bi : ai;
}
__device__ __forceinline__ void ceL(float& av, int& ai, float& bv, int& bi) {
    bool t = (bv < av) || (bv == av && bi < ai);
    float lv = t ? bv : av; int li = t ? bi : ai;
    float hv = t ? av : bv; int hi = t ? ai : bi;
    av = lv; ai = li; bv = hv; bi = hi;
}
// merge two sorted-4 lists (a mine, b other) -> lowest-4 sorted, into a.
// Bitonic: [a0..a3,b3..b0] lower-half CEs, then 4-sort of the bitonic half.
__device__ __forceinline__ void merge4(float& a0, int& i0, float& a1, int& i1,
                                       float& a2, int& i2, float& a3, int& i3,
                                       float b0, int j0, float b1, int j1,
                                       float b2, int j2, float b3, int j3) {
    float m0, m1, m2, m3; int n0, n1, n2, n3;
    minL(a0, i0, b3, j3, m0, n0);
    minL(a1, i1, b2, j2, m1, n1);
    minL(a2, i2, b1, j1, m2, n2);
    minL(a3, i3, b0, j0, m3, n3);
    ceL(m0, n0, m2, n2); ceL(m1, n1, m3, n3);
    ceL(m0, n0, m1, n1); ceL(m2, n2, m3, n3);
    a0 = m0; i0 = n0; a1 = m1; i1 = n1; a2 = m2; i2 = n2; a3 = m3; i3 = n3;
}

// ---------------------------------------------------------------------------
// MFMA screen: D[code][zrow] = e.z via 3-product bf16 split (structure verified
// r3/r4). Epilogue now tracks a per-row TOP-4 (value, idx) list so the fixup
// never rescans the codebook:
//   full (v3-v0 < TAU2, ~P=2e-4): exact rescan kernel
//   lite (v1-v0 < TAU2, ~5%):     exact compare among <=4 recorded candidates
// Correctness: codes outside top-4 have s >= v0+TAU2 = 2e-4 > worst-case
// |screen partial - (quantized ref - Z)| bound (~1.5e-4) -> cannot win.
__global__ __launch_bounds__(256, 2) void vq_mfma_kernel(
        const ushort* __restrict__ zh, const ushort* __restrict__ zl,
        const ushort* __restrict__ eh, const ushort* __restrict__ el,
        const float* __restrict__ enorm, const float* __restrict__ e,
        float* __restrict__ out, int* __restrict__ count,
        int* __restrict__ fullList, int* __restrict__ liteRow,
        int4* __restrict__ liteCand, int cap, int N, int K) {
    __shared__ __align__(16) ushort tiles[4][8192];   // 64 KB total

    const int tid = threadIdx.x;
    const int w = tid >> 6, lane = tid & 63;
    const int wm = w >> 1, wn = w & 1;
    const int n0 = blockIdx.x * 128;

    const ushort* tsrc = (w == 0) ? eh : (w == 1) ? el : (w == 2) ? zh : zl;
    const bool is_e = (w < 2);

    const int srow = lane >> 3;            // staging: row within 8-row group
    const int skg  = lane & 7;             // staging: k-group (8 ushorts)
    const int swz  = (skg ^ srow) * 8;     // swizzled k-offset (row&7 == srow)

    const ushort* EH = tiles[0];
    const ushort* EL = tiles[1];
    const ushort* ZH = tiles[2];
    const ushort* ZL = tiles[3];

    // per-lane sorted top-4 (value, idx) per acc-row b (lexicographic asc)
    float tv[4][4]; int ti[4][4];
    #pragma unroll
    for (int b = 0; b < 4; b++)
        #pragma unroll
        for (int k = 0; k < 4; k++) { tv[b][k] = 3.4e38f; ti[b][k] = 0x7fffffff; }

    const int rsel = lane & 15;

    for (int kt = 0; kt < K; kt += 128) {
        f32x4 acc[4][4];
        const f32x4 zero4 = {0.f, 0.f, 0.f, 0.f};
        #pragma unroll
        for (int a = 0; a < 4; a++)
            #pragma unroll
            for (int b = 0; b < 4; b++) acc[a][b] = zero4;

        const int rb = is_e ? kt : n0;
        const ushort* gsrc = tsrc + (size_t)(rb + srow) * DIM;

        for (int d0 = 0; d0 < DIM; d0 += 64) {
            // ---- stage this wave's tile: 128 rows x 64 k (16 KB) ----
            const ushort* gp = gsrc + d0 + skg * 8;
            {
                float4 stg[8];
                #pragma unroll
                for (int i = 0; i < 8; i++)
                    stg[i] = *(const float4*)(gp + (size_t)(8 * i) * DIM);
                #pragma unroll
                for (int i = 0; i < 8; i++)
                    *(float4*)&tiles[w][(8 * i + srow) * 64 + swz] = stg[i];
                #pragma unroll
                for (int i = 0; i < 8; i++)
                    stg[i] = *(const float4*)(gp + (size_t)(64 + 8 * i) * DIM);
                #pragma unroll
                for (int i = 0; i < 8; i++)
                    *(float4*)&tiles[w][(64 + 8 * i + srow) * 64 + swz] = stg[i];
            }
            __syncthreads();

            // ---- MFMA: 2 k-steps of 32, 3 products each ----
            #pragma unroll
            for (int c = 0; c < 2; c++) {
                const int rkg = ((c * 4 + (lane >> 4)) ^ (lane & 7)) * 8;
                bf16x8 Ah[4], Al[4];
                #pragma unroll
                for (int a = 0; a < 4; a++) {
                    int off = (wm * 64 + a * 16 + rsel) * 64 + rkg;
                    Ah[a] = *(const bf16x8*)&EH[off];
                    Al[a] = *(const bf16x8*)&EL[off];
                }
                #pragma unroll
                for (int b = 0; b < 4; b++) {
                    int off = (wn * 64 + b * 16 + rsel) * 64 + rkg;
                    bf16x8 Bh = *(const bf16x8*)&ZH[off];
                    bf16x8 Bl = *(const bf16x8*)&ZL[off];
                    #pragma unroll
                    for (int a = 0; a < 4; a++) {
                        acc[a][b] = __builtin_amdgcn_mfma_f32_16x16x32_bf16(Ah[a], Bh, acc[a][b], 0, 0, 0);
                        acc[a][b] = __builtin_amdgcn_mfma_f32_16x16x32_bf16(Al[a], Bh, acc[a][b], 0, 0, 0);
                        acc[a][b] = __builtin_amdgcn_mfma_f32_16x16x32_bf16(Ah[a], Bl, acc[a][b], 0, 0, 0);
                    }
                }
            }
            __syncthreads();
        }
        // epilogue: s = ||e||^2 - 2*dot; per-lane codes ascend (a outer, r
        // inner), so strict-< insertion keeps first-index order on value ties.
        const int hi4 = (lane >> 4) * 4;
        #pragma unroll
        for (int a = 0; a < 4; a++) {
            #pragma unroll
            for (int r = 0; r < 4; r++) {
                const int code = kt + wm * 64 + a * 16 + hi4 + r;
                const float en = enorm[code];   // 4KB, L1-resident
                #pragma unroll
                for (int b = 0; b < 4; b++) {
                    float s = fmaf(-2.f, acc[a][b][r], en);
                    if (s < tv[b][3]) {
                        bool p0 = s < tv[b][0], p1 = s < tv[b][1], p2 = s < tv[b][2];
                        tv[b][3] = p2 ? tv[b][2] : s;  ti[b][3] = p2 ? ti[b][2] : code;
                        if (p2) { tv[b][2] = p1 ? tv[b][1] : s; ti[b][2] = p1 ? ti[b][1] : code; }
                        if (p1) { tv[b][1] = p0 ? tv[b][0] : s; ti[b][1] = p0 ? ti[b][0] : code; }
                        if (p0) { tv[b][0] = s; ti[b][0] = code; }
                    }
                }
            }
        }
    }

    // merge across the 4 hi-groups (lanes l, l^16, l^32, l^48 share zrows)
    #pragma unroll
    for (int off = 16; off <= 32; off <<= 1) {
        #pragma unroll
        for (int b = 0; b < 4; b++) {
            float o0 = __shfl_xor(tv[b][0], off, 64);
            float o1 = __shfl_xor(tv[b][1], off, 64);
            float o2 = __shfl_xor(tv[b][2], off, 64);
            float o3 = __shfl_xor(tv[b][3], off, 64);
            int   q0 = __shfl_xor(ti[b][0], off, 64);
            int   q1 = __shfl_xor(ti[b][1], off, 64);
            int   q2 = __shfl_xor(ti[b][2], off, 64);
            int   q3 = __shfl_xor(ti[b][3], off, 64);
            merge4(tv[b][0], ti[b][0], tv[b][1], ti[b][1],
                   tv[b][2], ti[b][2], tv[b][3], ti[b][3],
                   o0, q0, o1, q1, o2, q2, o3, q3);
        }
    }

    // union across wm halves: [128 rows][2 wm][4 slots] in LDS (tiles dead)
    char* ub = (char*)tiles;
    float* mv = (float*)ub;              // 4 KB
    int*   mi = (int*)(ub + 4096);       // 4 KB
    int*   bestk = (int*)(ub + 8192);    // 512 B

    if (lane < 16) {
        #pragma unroll
        for (int b = 0; b < 4; b++) {
            int rl = wn * 64 + b * 16 + lane;
            #pragma unroll
            for (int k = 0; k < 4; k++) {
                mv[(rl * 2 + wm) * 4 + k] = tv[b][k];
                mi[(rl * 2 + wm) * 4 + k] = ti[b][k];
            }
        }
    }
    __syncthreads();
    if (tid < 128) {
        float a0 = mv[(tid*2+0)*4+0], a1 = mv[(tid*2+0)*4+1];
        float a2 = mv[(tid*2+0)*4+2], a3 = mv[(tid*2+0)*4+3];
        int   c0 = mi[(tid*2+0)*4+0], c1 = mi[(tid*2+0)*4+1];
        int   c2 = mi[(tid*2+0)*4+2], c3 = mi[(tid*2+0)*4+3];
        float b0 = mv[(tid*2+1)*4+0], b1 = mv[(tid*2+1)*4+1];
        float b2 = mv[(tid*2+1)*4+2], b3 = mv[(tid*2+1)*4+3];
        int   d0 = mi[(tid*2+1)*4+0], d1 = mi[(tid*2+1)*4+1];
        int   d2 = mi[(tid*2+1)*4+2], d3 = mi[(tid*2+1)*4+3];
        merge4(a0, c0, a1, c1, a2, c2, a3, c3,
               b0, d0, b1, d1, b2, d2, b3, d3);
        bestk[tid] = c0;
        if (count) {
            bool full = (a3 - a0 < TAU2);
            bool lite = !full && (a1 - a0 < TAU2);
            if (full) {
                int slot = atomicAdd(&count[0], 1);
                if (slot < cap) fullList[slot] = n0 + tid;
            } else if (lite) {
                int slot = atomicAdd(&count[1], 1);
                if (slot < cap) {
                    liteRow[slot] = n0 + tid;
                    int e1 = (a1 - a0 < TAU2) ? c1 : -1;
                    int e2 = (a2 - a0 < TAU2) ? c2 : -1;
                    liteCand[slot] = make_int4(c0, e1, e2, -1);
                }
            }
        }
    }
    __syncthreads();

    // Gather: out[row] = e[bestk[row]] (lite/full rows overwritten later)
    const float4* e4 = (const float4*)e;
    float4* o4 = (float4*)out;
    for (int j = tid; j < 128 * (DIM / 4); j += 256) {
        int row = j >> 7;
        int col = j & 127;
        o4[(size_t)(n0 + row) * (DIM / 4) + col] = e4[(size_t)bestk[row] * (DIM / 4) + col];
    }
}

// ---------------------------------------------------------------------------
// Lite fixup: one wave per flagged row; exact quantized-replica compare among
// the <=4 recorded candidates. D = fl32( fl32(Z+E_k) - 2*fl32(dot64) ),
// lexicographic (D, idx) -> reference argmin (candidates are a proven superset).
__global__ __launch_bounds__(256) void fixup_lite_kernel(
        const float* __restrict__ z, const float* __restrict__ e,
        const float* __restrict__ enorm, float* __restrict__ out,
        const int* __restrict__ count, const int* __restrict__ liteRow,
        const int4* __restrict__ liteCand, int cap) {
    if (!count) return;
    int cnt = count[1];
    if (cnt > cap) cnt = cap;
    const int lane = threadIdx.x & 63;
    const int wid = (blockIdx.x * 256 + threadIdx.x) >> 6;
    const int nw = gridDim.x * 4;
    for (int i = wid; i < cnt; i += nw) {
        const int row = liteRow[i];
        const int4 cd = liteCand[i];
        const float4* zr4 = (const float4*)(z + (size_t)row * DIM);
        float4 za = zr4[lane * 2], zb = zr4[lane * 2 + 1];
        // Z = fl32( fp64 sum of fl32(z*z) terms )
        float q0 = za.x*za.x, q1 = za.y*za.y, q2 = za.z*za.z, q3 = za.w*za.w;
        float q4 = zb.x*zb.x, q5 = zb.y*zb.y, q6 = zb.z*zb.z, q7 = zb.w*zb.w;
        double zs = ((double)q0 + (double)q1) + ((double)q2 + (double)q3)
                  + ((double)q4 + (double)q5) + ((double)q6 + (double)q7);
        #pragma unroll
        for (int off = 32; off > 0; off >>= 1) zs += __shfl_xor(zs, off, 64);
        const float Zs = (float)zs;
        float bD = 3.4e38f; int bI = 0x7fffffff;
        const int cds[4] = {cd.x, cd.y, cd.z, cd.w};
        #pragma unroll
        for (int j = 0; j < 4; j++) {
            const int c = cds[j];
            if (c < 0) continue;
            const float4* er4 = (const float4*)(e + (size_t)c * DIM);
            float4 ea = er4[lane * 2], eb = er4[lane * 2 + 1];
            double s = 0.0;
            s = fma((double)za.x, (double)ea.x, s);
            s = fma((double)za.y, (double)ea.y, s);
            s = fma((double)za.z, (double)ea.z, s);
            s = fma((double)za.w, (double)ea.w, s);
            s = fma((double)zb.x, (double)eb.x, s);
            s = fma((double)zb.y, (double)eb.y, s);
            s = fma((double)zb.z, (double)eb.z, s);
            s = fma((double)zb.w, (double)eb.w, s);
            #pragma unroll
            for (int off = 32; off > 0; off >>= 1) s += __shfl_xor(s, off, 64);
            float m = (float)s;              // fl32(dot64)
            float T = Zs + enorm[c];         // fl32(Z + E_k)
            float D = T - 2.0f * m;          // fl32(T - 2m)
            if (D < bD || (D == bD && c < bI)) { bD = D; bI = c; }
        }
        const float4* src = (const float4*)(e + (size_t)bI * DIM);
        float4* dst = (float4*)(out + (size_t)row * DIM);
        dst[lane * 2] = src[lane * 2];
        dst[lane * 2 + 1] = src[lane * 2 + 1];
    }
}

// ---------------------------------------------------------------------------
// Full fixup (r3-verified): per-row exact rescan of all K codes; handles the
// rare v3-v0 < TAU2 rows (expected ~10). Grid-strided one row per block.
__global__ __launch_bounds__(256) void fixup_full_kernel(const float* __restrict__ z,
                                                         const float* __restrict__ e,
                                                         const float* __restrict__ enorm,
                                                         float* __restrict__ out,
                                                         const int* __restrict__ count,
                                                         const int* __restrict__ list,
                                                         int cap, int K) {
    __shared__ double zd[DIM];
    __shared__ double rzd[256];
    __shared__ float Zrow;
    __shared__ float rv[256];
    __shared__ int   ri[256];
    if (!count) return;
    int cnt = count[0];
    if (cnt > cap) cnt = cap;
    for (int li = blockIdx.x; li < cnt; li += gridDim.x) {
        int row = list[li];
        __syncthreads();
        for (int j = threadIdx.x; j < DIM; j += 256) zd[j] = (double)z[(size_t)row*DIM + j];
        __syncthreads();
        {
            double p = 0.0;
            for (int j = threadIdx.x; j < DIM; j += 256) {
                float f = (float)zd[j]; float t = f * f; p += (double)t;
            }
            rzd[threadIdx.x] = p;
            __syncthreads();
            for (int st = 128; st > 0; st >>= 1) {
                if (threadIdx.x < st) rzd[threadIdx.x] += rzd[threadIdx.x + st];
                __syncthreads();
            }
            if (threadIdx.x == 0) Zrow = (float)rzd[0];
        }
        __syncthreads();
        float Zs = Zrow;
        float best = 3.4e38f;
        int bidx = 0x7fffffff;
        for (int c = threadIdx.x; c < K; c += 256) {
            const float4* er4 = (const float4*)(e + (size_t)c * DIM);
            double s = 0.0;
            #pragma unroll 4
            for (int d4 = 0; d4 < DIM/4; d4++) {
                float4 v = er4[d4];
                s = fma(zd[d4*4+0], (double)v.x, s);
                s = fma(zd[d4*4+1], (double)v.y, s);
                s = fma(zd[d4*4+2], (double)v.z, s);
                s = fma(zd[d4*4+3], (double)v.w, s);
            }
            float m = (float)s;
            float T = Zs + enorm[c];
            float D = T - 2.0f * m;
            if (D < best) { best = D; bidx = c; }
        }
        rv[threadIdx.x] = best;
        ri[threadIdx.x] = bidx;
        __syncthreads();
        for (int st = 128; st > 0; st >>= 1) {
            if (threadIdx.x < st) {
                float v2 = rv[threadIdx.x + st];
                int    i2 = ri[threadIdx.x + st];
                if (v2 < rv[threadIdx.x] ||
                    (v2 == rv[threadIdx.x] && i2 < ri[threadIdx.x])) {
                    rv[threadIdx.x] = v2;
                    ri[threadIdx.x] = i2;
                }
            }
            __syncthreads();
        }
        int bk = ri[0];
        const float4* src = (const float4*)(e + (size_t)bk * DIM);
        float4* dst = (float4*)(out + (size_t)row * DIM);
        for (int j = threadIdx.x; j < DIM/4; j += 256) dst[j] = src[j];
    }
}

// ---------------------------------------------------------------------------
// fp32 fallback screen (flags everything into the FULL list) — only used when
// ws is too small for the bf16 workspace.
__global__ __launch_bounds__(256, 2) void vq_kernel(const float* __restrict__ z,
                                                    const float* __restrict__ e,
                                                    const float* __restrict__ enorm,
                                                    float* __restrict__ out,
                                                    int* __restrict__ count,
                                                    int* __restrict__ list,
                                                    int cap, int N, int K) {
    __shared__ __align__(16) float zs[BD * LDP];
    __shared__ __align__(16) float es[BD * LDP];
    __shared__ float redv[BM * 16];
    __shared__ int   redi[BM * 16];
    __shared__ float reds[BM * 16];
    __shared__ int   bestk[BM];

    const int tid = threadIdx.x;
    const int tx = tid & 15;
    const int ty = tid >> 4;
    const int n0 = blockIdx.x * BM;

    float bv[8], sv[8];
    int   bi[8];
    #pragma unroll
    for (int i = 0; i < 8; i++) { bv[i] = 3.4e38f; sv[i] = 3.4e38f; bi[i] = 0; }

    for (int kt = 0; kt < K; kt += BK) {
        float acc[8][8];
        #pragma unroll
        for (int i = 0; i < 8; i++)
            #pragma unroll
            for (int j = 0; j < 8; j++) acc[i][j] = 0.f;

        for (int d0 = 0; d0 < DIM; d0 += BD) {
            #pragma unroll
            for (int l = 0; l < 4; l++) {
                int j = tid + l * 256;
                int row = j >> 3;
                int c = j & 7;
                float4 v = *(const float4*)(z + (size_t)(n0 + row) * DIM + d0 + c * 4);
                zs[(c*4+0)*LDP + row] = v.x;
                zs[(c*4+1)*LDP + row] = v.y;
                zs[(c*4+2)*LDP + row] = v.z;
                zs[(c*4+3)*LDP + row] = v.w;
                float4 w = *(const float4*)(e + (size_t)(kt + row) * DIM + d0 + c * 4);
                es[(c*4+0)*LDP + row] = w.x;
                es[(c*4+1)*LDP + row] = w.y;
                es[(c*4+2)*LDP + row] = w.z;
                es[(c*4+3)*LDP + row] = w.w;
            }
            __syncthreads();
            #pragma unroll 8
            for (int dd = 0; dd < BD; dd++) {
                float4 z0 = *(const float4*)&zs[dd*LDP + ty*8];
                float4 z1 = *(const float4*)&zs[dd*LDP + ty*8+4];
                float4 e0 = *(const float4*)&es[dd*LDP + tx*4];
                float4 e1 = *(const float4*)&es[dd*LDP + tx*4+64];
                float zr[8] = {z0.x, z0.y, z0.z, z0.w, z1.x, z1.y, z1.z, z1.w};
                float ek[8] = {e0.x, e0.y, e0.z, e0.w, e1.x, e1.y, e1.z, e1.w};
                #pragma unroll
                for (int i = 0; i < 8; i++)
                    #pragma unroll
                    for (int jj = 0; jj < 8; jj++)
                        acc[i][jj] = fmaf(zr[i], ek[jj], acc[i][jj]);
            }
            __syncthreads();
        }
        #pragma unroll
        for (int jj = 0; jj < 8; jj++) {
            int kk = kt + ((jj < 4) ? (tx*4 + jj) : (64 + tx*4 + (jj - 4)));
            float en = enorm[kk];
            #pragma unroll
            for (int i = 0; i < 8; i++) {
                float s = fmaf(-2.f, acc[i][jj], en);
                if (s < bv[i]) { sv[i] = bv[i]; bv[i] = s; bi[i] = kk; }
                else if (s < sv[i]) sv[i] = s;
            }
        }
    }

    #pragma unroll
    for (int i = 0; i < 8; i++) {
        int row = ty*8 + i;
        redv[row*16 + tx] = bv[i];
        redi[row*16 + tx] = bi[i];
        reds[row*16 + tx] = sv[i];
    }
    __syncthreads();
    if (tid < BM) {
        float v = redv[tid*16];
        int ix = redi[tid*16];
        float s2 = reds[tid*16];
        #pragma unroll
        for (int t = 1; t < 16; t++) {
            float v2 = redv[tid*16 + t];
            int i2 = redi[tid*16 + t];
            float s22 = reds[tid*16 + t];
            if (v2 < v || (v2 == v && i2 < ix)) { s2 = fminf(s22, v); v = v2; ix = i2; }
            else { s2 = fminf(s2, v2); }
        }
        bestk[tid] = ix;
        if (count && (s2 - v < TAU)) {
            int slot = atomicAdd(&count[0], 1);
            if (slot < cap) list[slot] = n0 + tid;
        }
    }
    __syncthreads();

    const float4* e4 = (const float4*)e;
    float4* o4 = (float4*)out;
    for (int j = tid; j < BM * (DIM / 4); j += 256) {
        int row = j >> 7;
        int col = j & 127;
        o4[(size_t)(n0 + row) * (DIM / 4) + col] = e4[(size_t)bestk[row] * (DIM / 4) + col];
    }
}

// ---------------------------------------------------------------------------
extern "C" void kernel_launch(void* const* d_in, const int* in_sizes, int n_in,
                              void* d_out, int out_size, void* d_ws, size_t ws_size,
                              hipStream_t stream) {
    const float* z = (const float*)d_in[0];
    const float* e = (const float*)d_in[1];
    float* out = (float*)d_out;
    const int N = in_sizes[0] / DIM;   // 65536
    const int K = in_sizes[1] / DIM;   // 1024

    // ws layout: [0,K) enorm | [K]=fullCnt [K+1]=liteCnt | fullList N |
    //            liteRow N | (16B-align) liteCand N int4 | (4KB-align)
    //            zh[N*D] zl[N*D] eh[K*D] el[K*D]  (bf16 as ushort)
    float* enorm = (float*)d_ws;
    long ws_elems = (long)(ws_size / 4);
    bool have_list = ws_elems >= K + 2;
    int* count = have_list ? ((int*)d_ws + K) : nullptr;
    int* fullList = have_list ? ((int*)d_ws + K + 2) : nullptr;
    int* liteRow  = have_list ? (fullList + N) : nullptr;

    size_t lc_off  = (((size_t)(K + 2 + 2 * N) * 4) + 15) & ~(size_t)15;
    int4* liteCand = (int4*)((char*)d_ws + lc_off);
    size_t base_b  = lc_off + (size_t)N * 16;
    size_t cvt_off = (base_b + 4095) & ~(size_t)4095;
    size_t zpart   = (size_t)N * DIM * 2;
    size_t epart   = (size_t)K * DIM * 2;
    size_t need    = cvt_off + 2 * zpart + 2 * epart;
    bool mfma_ok = have_list && ws_size >= need && K == 1024 && (N % 128) == 0;

    if (mfma_ok) {
        int cap = N;
        ushort* zh = (ushort*)((char*)d_ws + cvt_off);
        ushort* zl = zh + (size_t)N * DIM;
        ushort* eh = zl + (size_t)N * DIM;
        ushort* el = eh + (size_t)K * DIM;
        long nz4 = (long)N * (DIM / 4), ne4 = (long)K * (DIM / 4);
        cvt_kernel<<<dim3(2048), dim3(256), 0, stream>>>(z, e, zh, zl, eh, el, nz4, ne4);
        enorm_kernel<<<dim3((K + 3) / 4), dim3(256), 0, stream>>>(e, enorm, count, K);
        vq_mfma_kernel<<<dim3(N / 128), dim3(256), 0, stream>>>(zh, zl, eh, el, enorm, e,
                                                                out, count, fullList,
                                                                liteRow, liteCand, cap, N, K);
        fixup_lite_kernel<<<dim3(512), dim3(256), 0, stream>>>(z, e, enorm, out, count,
                                                               liteRow, liteCand, cap);
        fixup_full_kernel<<<dim3(1024), dim3(256), 0, stream>>>(z, e, enorm, out, count,
                                                                fullList, cap, K);
    } else {
        // emergency fp32 path: flag everything into full list
        long cap_l = have_list ? (ws_elems - K - 2) : 0;
        if (cap_l > N) cap_l = N;
        int cap = (int)cap_l;
        enorm_kernel<<<dim3((K + 3) / 4), dim3(256), 0, stream>>>(e, enorm, count, K);
        vq_kernel<<<dim3(N / BM), dim3(256), 0, stream>>>(z, e, enorm, out, count, fullList, cap, N, K);
        fixup_full_kernel<<<dim3(2048), dim3(256), 0, stream>>>(z, e, enorm, out, count,
                                                                fullList, cap, K);
    }
}